// Round 10
// baseline (2385.527 us; speedup 1.0000x reference)
//
#include <hip/hip_runtime.h>
#include <hip/hip_bf16.h>
#include <cmath>

#define DEVI __device__ __forceinline__

constexpr int Hn   = 2048;   // hidden
constexpr int In   = 1408;   // per-expert intermediate
constexpr int En   = 16;     // routed experts
constexpr int Kn   = 4;      // top-k
constexpr int ISHn = 2816;   // shared intermediate
constexpr int Tn   = 8192;   // tokens (B*S)
constexpr int Rn   = Tn * Kn; // total routed rows = 32768

typedef __attribute__((ext_vector_type(4))) float f32x4;
typedef __attribute__((ext_vector_type(8))) __bf16 bf16x8;
typedef __attribute__((ext_vector_type(8))) unsigned short u16x8;

DEVI unsigned short f2bf(float f) {
  unsigned int u = __builtin_bit_cast(unsigned int, f);
  unsigned int r = (u + 0x7fffu + ((u >> 16) & 1u)) >> 16;
  return (unsigned short)r;
}
DEVI float bf2f(unsigned short h) {
  return __builtin_bit_cast(float, (unsigned int)h << 16);
}

DEVI f32x4 mfma16(bf16x8 a, bf16x8 b, f32x4 c) {
  return __builtin_amdgcn_mfma_f32_16x16x32_bf16(a, b, c, 0, 0, 0);
}

DEVI bf16x8 lds_frag(const unsigned short* p) {
  return __builtin_bit_cast(bf16x8, *reinterpret_cast<const u16x8*>(p));
}

DEVI void gload_lds16(const void* src, void* dst) {
  __builtin_amdgcn_global_load_lds(
      (const __attribute__((address_space(1))) void*)src,
      (__attribute__((address_space(3))) void*)dst, 16, 0, 0);
}

// bijective XCD chunk remap (T1). Requires nwg % 8 == 0 (grids are by design).
// Dispatch round-robins bid across 8 XCDs; remap gives each XCD a CONTIGUOUS
// range of cache-blocked work-ids, so the 8 m8-blocks sharing a B panel (and
// the A-group n-sweep) stay on ONE XCD's L2.
DEVI int xcd_remap(int bid, int nwg) {
  return (bid & 7) * (nwg >> 3) + (bid >> 3);
}

// ---------------- fused fp32 -> bf16 conversion (6 weight tensors) ----------
DEVI void cvt_seg(const float* __restrict__ in, unsigned short* __restrict__ o,
                  long n8, long t0, long stride) {
  for (long v = t0; v < n8; v += stride) {
    const float4* s = reinterpret_cast<const float4*>(in + v * 8);
    float4 a = s[0], b = s[1];
    u16x8 r;
    r[0] = f2bf(a.x); r[1] = f2bf(a.y); r[2] = f2bf(a.z); r[3] = f2bf(a.w);
    r[4] = f2bf(b.x); r[5] = f2bf(b.y); r[6] = f2bf(b.z); r[7] = f2bf(b.w);
    reinterpret_cast<u16x8*>(o)[v] = r;
  }
}

__global__ __launch_bounds__(256)
void cvt_all(const float* __restrict__ Wg, unsigned short* __restrict__ wgq,
             const float* __restrict__ Wu, unsigned short* __restrict__ wuq,
             const float* __restrict__ Wd, unsigned short* __restrict__ wdq,
             const float* __restrict__ Sg, unsigned short* __restrict__ sgq,
             const float* __restrict__ Su, unsigned short* __restrict__ suq,
             const float* __restrict__ Sd, unsigned short* __restrict__ sdq) {
  long stride = (long)gridDim.x * blockDim.x;
  long t0 = blockIdx.x * (long)blockDim.x + threadIdx.x;
  const long n8_w = (long)En * In * Hn / 8;
  const long n8_s = (long)ISHn * Hn / 8;
  cvt_seg(Wg, wgq, n8_w, t0, stride);
  cvt_seg(Wu, wuq, n8_w, t0, stride);
  cvt_seg(Wd, wdq, n8_w, t0, stride);
  cvt_seg(Sg, sgq, n8_s, t0, stride);
  cvt_seg(Su, suq, n8_s, t0, stride);
  cvt_seg(Sd, sdq, n8_s, t0, stride);
}

// ---------------- zero counts + cursor ----------------
__global__ void zero_k(int* p) { p[threadIdx.x] = 0; }

// ---------------- router: one wave per token, fp64 scoring; also emits xb ----
__global__ __launch_bounds__(256)
void router_k(const float* __restrict__ x, const float* __restrict__ rg,
              const float* __restrict__ ru, const float* __restrict__ esc,
              const float* __restrict__ ebi, int* __restrict__ counts,
              int* __restrict__ topk, float* __restrict__ wval,
              unsigned short* __restrict__ xb) {
  int w = (blockIdx.x * blockDim.x + threadIdx.x) >> 6;
  int lane = threadIdx.x & 63;
  if (w >= Tn) return;
  const float* xr = x + (size_t)w * Hn;
  float xv[Hn / 64];
#pragma unroll
  for (int j = 0; j < Hn / 64; ++j) xv[j] = xr[lane + j * 64];

  // emit bf16 x (fused conversion; x read exactly once)
  unsigned short* xbr = xb + (size_t)w * Hn;
#pragma unroll
  for (int j = 0; j < Hn / 64; ++j) xbr[lane + j * 64] = f2bf(xv[j]);

  double pr[En];
  double mx = -1e300;
#pragma unroll
  for (int e = 0; e < En; ++e) {
    const float* gr = rg + (size_t)e * Hn;
    const float* ur = ru + (size_t)e * Hn;
    double pg = 0.0, pu = 0.0;
#pragma unroll
    for (int j = 0; j < Hn / 64; ++j) {
      pg += (double)xv[j] * (double)gr[lane + j * 64];
      pu += (double)xv[j] * (double)ur[lane + j * 64];
    }
#pragma unroll
    for (int s = 32; s > 0; s >>= 1) {
      pg += __shfl_xor(pg, s);
      pu += __shfl_xor(pu, s);
    }
    double sg = pg / (1.0 + exp(-pg));     // silu
    double sc = fabs(pu * sg);
    pr[e] = sc;
    mx = fmax(mx, sc);
  }
  double den = 0.0;
#pragma unroll
  for (int e = 0; e < En; ++e) { pr[e] = exp(pr[e] - mx); den += pr[e]; }

  if (lane == 0) {
    double invden = 1.0 / den;
    unsigned chosen = 0;
    for (int k = 0; k < Kn; ++k) {
      double bv = -1e300; int best = 0;
#pragma unroll
      for (int e = 0; e < En; ++e) {
        double be = pr[e] * invden + (double)ebi[e];
        if (!((chosen >> e) & 1u) && be > bv) { bv = be; best = e; }
      }
      chosen |= 1u << best;
      topk[w * Kn + k] = best;
      double pbest = bv - (double)ebi[best];
      wval[w * Kn + k] = (float)(1.0 + pbest * (double)esc[best]);
      atomicAdd(&counts[best], 1);
    }
  }
}

// ---------------- prefix over expert counts ----------------
__global__ void prefix_k(const int* __restrict__ counts, int* __restrict__ off) {
  if (threadIdx.x == 0) {
    int a = 0;
    for (int e = 0; e < En; ++e) { off[e] = a; a += counts[e]; }
    off[En] = a;
  }
}

// ---------------- build per-expert token lists + token->row map ----------------
__global__ void build_k(const int* __restrict__ topk, const float* __restrict__ wval,
                        const int* __restrict__ off, int* __restrict__ cursor,
                        int* __restrict__ list, float* __restrict__ cw,
                        int* __restrict__ rowOf) {
  int t = blockIdx.x * blockDim.x + threadIdx.x;
  if (t >= Tn) return;
  for (int k = 0; k < Kn; ++k) {
    int e = topk[t * Kn + k];
    int pos = atomicAdd(&cursor[e], 1);
    int r = off[e] + pos;
    list[r] = t;
    cw[r] = wval[t * Kn + k];
    rowOf[t * Kn + k] = r;
  }
}

// ======================================================================
// GEMMs: round-8 winner (128-row tiles, single-buffer 32KB LDS, swizzled,
// global_load_lds, 2 barriers/K-step), cache-blocked order (e, mg, n, m8)
// + bijective XCD chunk remap so same-B-panel blocks share one XCD L2.
// ======================================================================

// upA: h = silu(A@Bg^T) * (A@Bu^T). Block computes 128 rows x 64 cols of h.
// Bs rows 0-63 = Bg rows n0.., rows 64-127 = Bu rows (same cols).
// Fragment n=0,1 -> g, n=2,3 -> u of the SAME output columns (same thread).
__global__ __launch_bounds__(256, 2)
void upA_k(const unsigned short* __restrict__ xb,
           const unsigned short* __restrict__ WgA, const unsigned short* __restrict__ WuA,
           const unsigned short* __restrict__ SgA, const unsigned short* __restrict__ SuA,
           const int* __restrict__ list, const int* __restrict__ off,
           const int* __restrict__ counts,
           unsigned short* __restrict__ hrt, unsigned short* __restrict__ hsh) {
  constexpr int NTr = In / 64;              // 22
  constexpr int RT  = En * NTr * 64;        // 22528 routed tiles
  int w = xcd_remap(blockIdx.x, gridDim.x);
  int mi, n0, Nhalf, cnt, offE;
  const unsigned short *bg, *bu;
  unsigned short* hb;
  bool gat;
  if (w < RT) {
    int e  = w / (NTr * 64);                // /1408
    int r  = w - e * (NTr * 64);
    int mg = r / (NTr * 8);                 // /176
    int r2 = r - mg * (NTr * 8);
    int ni = r2 >> 3, m8 = r2 & 7;
    mi = (mg << 3) | m8;
    cnt = counts[e]; offE = off[e]; Nhalf = In; n0 = ni * 64;
    size_t es = (size_t)In * Hn;
    bg = WgA + (size_t)e * es; bu = WuA + (size_t)e * es;
    hb = hrt; gat = true;
  } else {
    int w2 = w - RT;                        // shared: 64 M x 44 N = 2816
    int mg = w2 / (44 * 8);                 // /352
    int r2 = w2 - mg * (44 * 8);
    int ni = r2 >> 3, m8 = r2 & 7;
    mi = (mg << 3) | m8;
    cnt = Tn; offE = 0; Nhalf = ISHn; n0 = ni * 64;
    bg = SgA; bu = SuA; hb = hsh; gat = false;
  }
  int m0 = mi * 128;
  if (m0 >= cnt) return;

  __shared__ alignas(16) unsigned short As[128 * 64];
  __shared__ alignas(16) unsigned short Bs[128 * 64];

  int tid = threadIdx.x, lane = tid & 63, wv = tid >> 6;
  int wm = wv >> 1, wn = wv & 1;

  const unsigned short* gA[4];
  const unsigned short* gB[4];
#pragma unroll
  for (int i = 0; i < 4; ++i) {
    int idx = i * 256 + tid;
    int row = idx >> 3, ch = idx & 7;
    int sch = ch ^ (row & 7);
    int rc = m0 + row; rc = rc < cnt ? rc : cnt - 1;
    int tok = gat ? list[offE + rc] : rc;
    gA[i] = xb + (size_t)tok * Hn + sch * 8;
    const unsigned short* bb = (row < 64) ? (bg + (size_t)(n0 + row) * Hn)
                                          : (bu + (size_t)(n0 + row - 64) * Hn);
    gB[i] = bb + sch * 8;
  }

  int aOff[4], bOff[4];
#pragma unroll
  for (int m = 0; m < 4; ++m) aOff[m] = (wm * 64 + m * 16 + (lane & 15)) * 64;
#pragma unroll
  for (int n = 0; n < 4; ++n)
    bOff[n] = ((n >> 1) * 64 + wn * 32 + (n & 1) * 16 + (lane & 15)) * 64;

  f32x4 acc[4][4];
#pragma unroll
  for (int m = 0; m < 4; ++m)
#pragma unroll
    for (int n = 0; n < 4; ++n) acc[m][n] = f32x4{0.f, 0.f, 0.f, 0.f};

  for (int kb = 0; kb < Hn / 64; ++kb) {
#pragma unroll
    for (int i = 0; i < 4; ++i)
      gload_lds16(gA[i] + kb * 64, &As[i * 2048 + wv * 512]);
#pragma unroll
    for (int i = 0; i < 4; ++i)
      gload_lds16(gB[i] + kb * 64, &Bs[i * 2048 + wv * 512]);
    __syncthreads();
#pragma unroll
    for (int kk = 0; kk < 2; ++kk) {
      int soff = (((kk * 4 + (lane >> 4)) ^ (lane & 7)) << 3);
      bf16x8 a[4], b[4];
#pragma unroll
      for (int m = 0; m < 4; ++m) a[m] = lds_frag(&As[aOff[m] + soff]);
#pragma unroll
      for (int n = 0; n < 4; ++n) b[n] = lds_frag(&Bs[bOff[n] + soff]);
#pragma unroll
      for (int m = 0; m < 4; ++m)
#pragma unroll
        for (int n = 0; n < 4; ++n)
          acc[m][n] = mfma16(a[m], b[n], acc[m][n]);
    }
    __syncthreads();
  }

#pragma unroll
  for (int m = 0; m < 4; ++m) {
#pragma unroll
    for (int j = 0; j < 4; ++j) {
      int r = wm * 64 + m * 16 + (lane >> 4) * 4 + j;
      if (m0 + r < cnt) {
#pragma unroll
        for (int n = 0; n < 2; ++n) {
          int col = n0 + wn * 32 + n * 16 + (lane & 15);
          float g = acc[m][n][j], u = acc[m][n + 2][j];
          float h = (g / (1.f + __expf(-g))) * u;
          hb[(size_t)(offE + m0 + r) * Nhalf + col] = f2bf(h);
        }
      }
    }
  }
}

// downA: C = h @ B^T. Routed region -> bf16*coef stores to yb;
// shared region -> plain f32 stores to out.
__global__ __launch_bounds__(256, 2)
void downA_k(const unsigned short* __restrict__ hrt, const unsigned short* __restrict__ hsh,
             const unsigned short* __restrict__ wdq, const unsigned short* __restrict__ sdq,
             const int* __restrict__ off, const int* __restrict__ counts,
             const float* __restrict__ cw,
             float* __restrict__ out, unsigned short* __restrict__ yb) {
  constexpr int NT = Hn / 128;              // 16
  constexpr int RT = En * NT * 64;          // 16384 routed tiles
  int w = xcd_remap(blockIdx.x, gridDim.x);
  int mi, n0, Kdim, cnt, offE;
  const unsigned short *bq, *hbuf;
  bool toYB;
  if (w < RT) {
    int e  = w >> 10;                       // / (16*64)
    int r  = w & 1023;
    int mg = r >> 7;                        // / (16*8)
    int r2 = r & 127;
    int ni = r2 >> 3, m8 = r2 & 7;
    mi = (mg << 3) | m8;
    cnt = counts[e]; offE = off[e]; Kdim = In; n0 = ni * 128;
    bq = wdq + (size_t)e * Hn * In; hbuf = hrt; toYB = true;
  } else {
    int w2 = w - RT;                        // shared: 64 M x 16 N = 1024
    int mg = w2 >> 7;
    int r2 = w2 & 127;
    int ni = r2 >> 3, m8 = r2 & 7;
    mi = (mg << 3) | m8;
    cnt = Tn; offE = 0; Kdim = ISHn; n0 = ni * 128;
    bq = sdq; hbuf = hsh; toYB = false;
  }
  int m0 = mi * 128;
  if (m0 >= cnt) return;

  __shared__ alignas(16) unsigned short As[128 * 64];
  __shared__ alignas(16) unsigned short Bs[128 * 64];

  int tid = threadIdx.x, lane = tid & 63, wv = tid >> 6;
  int wm = wv >> 1, wn = wv & 1;

  const unsigned short* gA[4];
  const unsigned short* gB[4];
#pragma unroll
  for (int i = 0; i < 4; ++i) {
    int idx = i * 256 + tid;
    int row = idx >> 3, ch = idx & 7;
    int sch = ch ^ (row & 7);
    int rc = m0 + row; rc = rc < cnt ? rc : cnt - 1;
    gA[i] = hbuf + (size_t)(offE + rc) * Kdim + sch * 8;
    gB[i] = bq + (size_t)(n0 + row) * Kdim + sch * 8;
  }

  int aOff[4], bOff[4];
#pragma unroll
  for (int m = 0; m < 4; ++m) aOff[m] = (wm * 64 + m * 16 + (lane & 15)) * 64;
#pragma unroll
  for (int n = 0; n < 4; ++n) bOff[n] = (wn * 64 + n * 16 + (lane & 15)) * 64;

  f32x4 acc[4][4];
#pragma unroll
  for (int m = 0; m < 4; ++m)
#pragma unroll
    for (int n = 0; n < 4; ++n) acc[m][n] = f32x4{0.f, 0.f, 0.f, 0.f};

  int nkb = Kdim / 64;
  for (int kb = 0; kb < nkb; ++kb) {
#pragma unroll
    for (int i = 0; i < 4; ++i)
      gload_lds16(gA[i] + kb * 64, &As[i * 2048 + wv * 512]);
#pragma unroll
    for (int i = 0; i < 4; ++i)
      gload_lds16(gB[i] + kb * 64, &Bs[i * 2048 + wv * 512]);
    __syncthreads();
#pragma unroll
    for (int kk = 0; kk < 2; ++kk) {
      int soff = (((kk * 4 + (lane >> 4)) ^ (lane & 7)) << 3);
      bf16x8 a[4], b[4];
#pragma unroll
      for (int m = 0; m < 4; ++m) a[m] = lds_frag(&As[aOff[m] + soff]);
#pragma unroll
      for (int n = 0; n < 4; ++n) b[n] = lds_frag(&Bs[bOff[n] + soff]);
#pragma unroll
      for (int m = 0; m < 4; ++m)
#pragma unroll
        for (int n = 0; n < 4; ++n)
          acc[m][n] = mfma16(a[m], b[n], acc[m][n]);
    }
    __syncthreads();
  }

#pragma unroll
  for (int m = 0; m < 4; ++m) {
#pragma unroll
    for (int j = 0; j < 4; ++j) {
      int r = wm * 64 + m * 16 + (lane >> 4) * 4 + j;
      if (m0 + r < cnt) {
        float coef = 1.f;
        if (toYB) coef = cw[offE + m0 + r];
#pragma unroll
        for (int n = 0; n < 4; ++n) {
          int col = n0 + wn * 64 + n * 16 + (lane & 15);
          float v = acc[m][n][j] * coef;
          if (toYB) yb[(size_t)(offE + m0 + r) * Hn + col] = f2bf(v);
          else out[(size_t)(m0 + r) * Hn + col] = v;
        }
      }
    }
  }
}

// ---------------- combine: out[t] += sum_k yb[rowOf[t,k]] ----------------
__global__ __launch_bounds__(256)
void combine_k(const unsigned short* __restrict__ yb, const int* __restrict__ rowOf,
               float* __restrict__ out) {
  int t = blockIdx.x;
  int c = threadIdx.x * 8;
  float* op = out + (size_t)t * Hn + c;
  float4 a0 = *reinterpret_cast<float4*>(op);
  float4 a1 = *reinterpret_cast<float4*>(op + 4);
#pragma unroll
  for (int k = 0; k < Kn; ++k) {
    int r = rowOf[t * Kn + k];
    u16x8 v = *reinterpret_cast<const u16x8*>(yb + (size_t)r * Hn + c);
    a0.x += bf2f(v[0]); a0.y += bf2f(v[1]); a0.z += bf2f(v[2]); a0.w += bf2f(v[3]);
    a1.x += bf2f(v[4]); a1.y += bf2f(v[5]); a1.z += bf2f(v[6]); a1.w += bf2f(v[7]);
  }
  *reinterpret_cast<float4*>(op) = a0;
  *reinterpret_cast<float4*>(op + 4) = a1;
}

// ======================================================================
extern "C" void kernel_launch(void* const* d_in, const int* in_sizes, int n_in,
                              void* d_out, int out_size, void* d_ws, size_t ws_size,
                              hipStream_t stream) {
  const float* x   = (const float*)d_in[0];
  const float* rg  = (const float*)d_in[1];
  const float* ru  = (const float*)d_in[2];
  const float* esc = (const float*)d_in[3];
  const float* ebi = (const float*)d_in[4];
  const float* Wg  = (const float*)d_in[5];
  const float* Wu  = (const float*)d_in[6];
  const float* Wd  = (const float*)d_in[7];
  const float* Sg  = (const float*)d_in[8];
  const float* Su  = (const float*)d_in[9];
  const float* Sd  = (const float*)d_in[10];
  float* out = (float*)d_out;

  char* ws = (char*)d_ws;

  const size_t sz_xb  = (size_t)Tn * Hn * 2;           //  33.6 MB
  const size_t sz_wgu = (size_t)En * In * Hn * 2;      //  92.3 MB each (wg,wu,wd)
  const size_t sz_sgu = (size_t)ISHn * Hn * 2;         //  11.5 MB each (sg,su,sd)
  const size_t sz_hrt = (size_t)Rn * In * 2;           //  92.3 MB
  const size_t sz_hsh = (size_t)Tn * ISHn * 2;         //  46.1 MB
  const size_t sz_misc = 1 << 20;

  size_t o = 0;
  auto take = [&](size_t b) { size_t r = o; o += (b + 255) & ~(size_t)255; return r; };
  size_t o_xb  = take(sz_xb);
  size_t o_wg  = take(sz_wgu);
  size_t o_wu  = take(sz_wgu);
  size_t o_wd  = take(sz_wgu);
  size_t o_sg  = take(sz_sgu);
  size_t o_su  = take(sz_sgu);
  size_t o_sd  = take(sz_sgu);
  size_t o_hrt = take(sz_hrt);
  size_t o_hsh = take(sz_hsh);
  size_t o_mi  = take(sz_misc);

  unsigned short* xb  = (unsigned short*)(ws + o_xb);
  unsigned short* wgq = (unsigned short*)(ws + o_wg);
  unsigned short* wuq = (unsigned short*)(ws + o_wu);
  unsigned short* wdq = (unsigned short*)(ws + o_wd);
  unsigned short* sgq = (unsigned short*)(ws + o_sg);
  unsigned short* suq = (unsigned short*)(ws + o_su);
  unsigned short* sdq = (unsigned short*)(ws + o_sd);
  unsigned short* hrt = (unsigned short*)(ws + o_hrt);
  unsigned short* hsh = (unsigned short*)(ws + o_hsh);
  char* misc = ws + o_mi;
  int*   counts = (int*)(misc);
  int*   cursor = (int*)(misc + 64);
  int*   off    = (int*)(misc + 128);
  int*   topk   = (int*)(misc + 256);
  float* wval   = (float*)(misc + 256 + 131072);
  int*   list   = (int*)(misc + 256 + 2 * 131072);
  float* cw     = (float*)(misc + 256 + 3 * 131072);
  int*   rowOf  = (int*)(misc + 256 + 4 * 131072);
  // yb aliases wg+wu bf16 region (dead after up kernel): 134.2 MB <= 184.6 MB
  unsigned short* yb = wgq;

  zero_k<<<1, 32, 0, stream>>>(counts);
  router_k<<<2048, 256, 0, stream>>>(x, rg, ru, esc, ebi, counts, topk, wval, xb);
  cvt_all<<<2048, 256, 0, stream>>>(Wg, wgq, Wu, wuq, Wd, wdq,
                                    Sg, sgq, Su, suq, Sd, sdq);
  prefix_k<<<1, 64, 0, stream>>>(counts, off);
  build_k<<<Tn / 256, 256, 0, stream>>>(topk, wval, off, cursor, list, cw, rowOf);

  // merged up: routed 22528 tiles + shared 2816 tiles (cache-blocked + XCD remap)
  upA_k<<<En * (In / 64) * 64 + 64 * (ISHn / 64), 256, 0, stream>>>(
      xb, wgq, wuq, sgq, suq, list, off, counts, hrt, hsh);
  // merged down: routed 16384 tiles + shared 1024 tiles
  downA_k<<<En * (Hn / 128) * 64 + 64 * (Hn / 128), 256, 0, stream>>>(
      hrt, hsh, wdq, sdq, off, counts, cw, out, yb);
  combine_k<<<Tn, 256, 0, stream>>>(yb, rowOf, out);
}

// Round 11
// 1706.215 us; speedup vs baseline: 1.3981x; 1.3981x over previous
//
#include <hip/hip_runtime.h>
#include <hip/hip_bf16.h>
#include <cmath>

#define DEVI __device__ __forceinline__

constexpr int Hn   = 2048;   // hidden
constexpr int In   = 1408;   // per-expert intermediate
constexpr int En   = 16;     // routed experts
constexpr int Kn   = 4;      // top-k
constexpr int ISHn = 2816;   // shared intermediate
constexpr int Tn   = 8192;   // tokens (B*S)
constexpr int Rn   = Tn * Kn; // total routed rows = 32768

typedef __attribute__((ext_vector_type(4))) float f32x4;
typedef __attribute__((ext_vector_type(8))) __bf16 bf16x8;
typedef __attribute__((ext_vector_type(8))) unsigned short u16x8;

DEVI unsigned short f2bf(float f) {
  unsigned int u = __builtin_bit_cast(unsigned int, f);
  unsigned int r = (u + 0x7fffu + ((u >> 16) & 1u)) >> 16;
  return (unsigned short)r;
}
DEVI float bf2f(unsigned short h) {
  return __builtin_bit_cast(float, (unsigned int)h << 16);
}

DEVI f32x4 mfma16(bf16x8 a, bf16x8 b, f32x4 c) {
  return __builtin_amdgcn_mfma_f32_16x16x32_bf16(a, b, c, 0, 0, 0);
}

DEVI bf16x8 lds_frag(const unsigned short* p) {
  return __builtin_bit_cast(bf16x8, *reinterpret_cast<const u16x8*>(p));
}

DEVI void gload_lds16(const void* src, void* dst) {
  __builtin_amdgcn_global_load_lds(
      (const __attribute__((address_space(1))) void*)src,
      (__attribute__((address_space(3))) void*)dst, 16, 0, 0);
}

// ---------------- fused fp32 -> bf16 conversion (6 weight tensors) ----------
DEVI void cvt_seg(const float* __restrict__ in, unsigned short* __restrict__ o,
                  long n8, long t0, long stride) {
  for (long v = t0; v < n8; v += stride) {
    const float4* s = reinterpret_cast<const float4*>(in + v * 8);
    float4 a = s[0], b = s[1];
    u16x8 r;
    r[0] = f2bf(a.x); r[1] = f2bf(a.y); r[2] = f2bf(a.z); r[3] = f2bf(a.w);
    r[4] = f2bf(b.x); r[5] = f2bf(b.y); r[6] = f2bf(b.z); r[7] = f2bf(b.w);
    reinterpret_cast<u16x8*>(o)[v] = r;
  }
}

__global__ __launch_bounds__(256)
void cvt_all(const float* __restrict__ Wg, unsigned short* __restrict__ wgq,
             const float* __restrict__ Wu, unsigned short* __restrict__ wuq,
             const float* __restrict__ Wd, unsigned short* __restrict__ wdq,
             const float* __restrict__ Sg, unsigned short* __restrict__ sgq,
             const float* __restrict__ Su, unsigned short* __restrict__ suq,
             const float* __restrict__ Sd, unsigned short* __restrict__ sdq) {
  long stride = (long)gridDim.x * blockDim.x;
  long t0 = blockIdx.x * (long)blockDim.x + threadIdx.x;
  const long n8_w = (long)En * In * Hn / 8;
  const long n8_s = (long)ISHn * Hn / 8;
  cvt_seg(Wg, wgq, n8_w, t0, stride);
  cvt_seg(Wu, wuq, n8_w, t0, stride);
  cvt_seg(Wd, wdq, n8_w, t0, stride);
  cvt_seg(Sg, sgq, n8_s, t0, stride);
  cvt_seg(Su, suq, n8_s, t0, stride);
  cvt_seg(Sd, sdq, n8_s, t0, stride);
}

// ---------------- zero counts + cursor ----------------
__global__ void zero_k(int* p) { p[threadIdx.x] = 0; }

// ---------------- router: one wave per token, fp64 scoring; also emits xb ----
__global__ __launch_bounds__(256)
void router_k(const float* __restrict__ x, const float* __restrict__ rg,
              const float* __restrict__ ru, const float* __restrict__ esc,
              const float* __restrict__ ebi, int* __restrict__ counts,
              int* __restrict__ topk, float* __restrict__ wval,
              unsigned short* __restrict__ xb) {
  int w = (blockIdx.x * blockDim.x + threadIdx.x) >> 6;
  int lane = threadIdx.x & 63;
  if (w >= Tn) return;
  const float* xr = x + (size_t)w * Hn;
  float xv[Hn / 64];
#pragma unroll
  for (int j = 0; j < Hn / 64; ++j) xv[j] = xr[lane + j * 64];

  // emit bf16 x (fused conversion; x read exactly once)
  unsigned short* xbr = xb + (size_t)w * Hn;
#pragma unroll
  for (int j = 0; j < Hn / 64; ++j) xbr[lane + j * 64] = f2bf(xv[j]);

  double pr[En];
  double mx = -1e300;
#pragma unroll
  for (int e = 0; e < En; ++e) {
    const float* gr = rg + (size_t)e * Hn;
    const float* ur = ru + (size_t)e * Hn;
    double pg = 0.0, pu = 0.0;
#pragma unroll
    for (int j = 0; j < Hn / 64; ++j) {
      pg += (double)xv[j] * (double)gr[lane + j * 64];
      pu += (double)xv[j] * (double)ur[lane + j * 64];
    }
#pragma unroll
    for (int s = 32; s > 0; s >>= 1) {
      pg += __shfl_xor(pg, s);
      pu += __shfl_xor(pu, s);
    }
    double sg = pg / (1.0 + exp(-pg));     // silu
    double sc = fabs(pu * sg);
    pr[e] = sc;
    mx = fmax(mx, sc);
  }
  double den = 0.0;
#pragma unroll
  for (int e = 0; e < En; ++e) { pr[e] = exp(pr[e] - mx); den += pr[e]; }

  if (lane == 0) {
    double invden = 1.0 / den;
    unsigned chosen = 0;
    for (int k = 0; k < Kn; ++k) {
      double bv = -1e300; int best = 0;
#pragma unroll
      for (int e = 0; e < En; ++e) {
        double be = pr[e] * invden + (double)ebi[e];
        if (!((chosen >> e) & 1u) && be > bv) { bv = be; best = e; }
      }
      chosen |= 1u << best;
      topk[w * Kn + k] = best;
      double pbest = bv - (double)ebi[best];
      wval[w * Kn + k] = (float)(1.0 + pbest * (double)esc[best]);
      atomicAdd(&counts[best], 1);
    }
  }
}

// ---------------- prefix over expert counts ----------------
__global__ void prefix_k(const int* __restrict__ counts, int* __restrict__ off) {
  if (threadIdx.x == 0) {
    int a = 0;
    for (int e = 0; e < En; ++e) { off[e] = a; a += counts[e]; }
    off[En] = a;
  }
}

// ---------------- build per-expert token lists + token->row map ----------------
__global__ void build_k(const int* __restrict__ topk, const float* __restrict__ wval,
                        const int* __restrict__ off, int* __restrict__ cursor,
                        int* __restrict__ list, float* __restrict__ cw,
                        int* __restrict__ rowOf) {
  int t = blockIdx.x * blockDim.x + threadIdx.x;
  if (t >= Tn) return;
  for (int k = 0; k < Kn; ++k) {
    int e = topk[t * Kn + k];
    int pos = atomicAdd(&cursor[e], 1);
    int r = off[e] + pos;
    list[r] = t;
    cw[r] = wval[t * Kn + k];
    rowOf[t * Kn + k] = r;
  }
}

// ======================================================================
// GEMMs: proven 2-barrier inner loop (128-row tiles, single-buffer 32KB
// LDS, XOR-swizzled, global_load_lds staging). Merged routed+shared 1D
// grids with CACHE-BLOCKED work order: (e, m-group-of-8, n, m-within).
// Default (round-robin) dispatch — XCD chunk remap measured -67% here
// (parallel L2 fill beats locality for this latency-bound staging loop).
// ======================================================================

// upA: h = silu(A@Bg^T) * (A@Bu^T). Block computes 128 rows x 64 cols of h.
// Bs rows 0-63 = Bg rows n0.., rows 64-127 = Bu rows (same cols).
// Fragment n=0,1 -> g, n=2,3 -> u of the SAME output columns (same thread).
__global__ __launch_bounds__(256, 2)
void upA_k(const unsigned short* __restrict__ xb,
           const unsigned short* __restrict__ WgA, const unsigned short* __restrict__ WuA,
           const unsigned short* __restrict__ SgA, const unsigned short* __restrict__ SuA,
           const int* __restrict__ list, const int* __restrict__ off,
           const int* __restrict__ counts,
           unsigned short* __restrict__ hrt, unsigned short* __restrict__ hsh) {
  constexpr int NTr = In / 64;              // 22
  constexpr int RT  = En * NTr * 64;        // 22528 routed tiles
  int w = blockIdx.x;
  int mi, n0, Nhalf, cnt, offE;
  const unsigned short *bg, *bu;
  unsigned short* hb;
  bool gat;
  if (w < RT) {
    int e  = w / (NTr * 64);                // /1408
    int r  = w - e * (NTr * 64);
    int mg = r / (NTr * 8);                 // /176
    int r2 = r - mg * (NTr * 8);
    int ni = r2 >> 3, m8 = r2 & 7;
    mi = (mg << 3) | m8;
    cnt = counts[e]; offE = off[e]; Nhalf = In; n0 = ni * 64;
    size_t es = (size_t)In * Hn;
    bg = WgA + (size_t)e * es; bu = WuA + (size_t)e * es;
    hb = hrt; gat = true;
  } else {
    int w2 = w - RT;                        // shared: 64 M x 44 N = 2816
    int mg = w2 / (44 * 8);                 // /352
    int r2 = w2 - mg * (44 * 8);
    int ni = r2 >> 3, m8 = r2 & 7;
    mi = (mg << 3) | m8;
    cnt = Tn; offE = 0; Nhalf = ISHn; n0 = ni * 64;
    bg = SgA; bu = SuA; hb = hsh; gat = false;
  }
  int m0 = mi * 128;
  if (m0 >= cnt) return;

  __shared__ alignas(16) unsigned short As[128 * 64];
  __shared__ alignas(16) unsigned short Bs[128 * 64];

  int tid = threadIdx.x, lane = tid & 63, wv = tid >> 6;
  int wm = wv >> 1, wn = wv & 1;

  const unsigned short* gA[4];
  const unsigned short* gB[4];
#pragma unroll
  for (int i = 0; i < 4; ++i) {
    int idx = i * 256 + tid;
    int row = idx >> 3, ch = idx & 7;
    int sch = ch ^ (row & 7);
    int rc = m0 + row; rc = rc < cnt ? rc : cnt - 1;
    int tok = gat ? list[offE + rc] : rc;
    gA[i] = xb + (size_t)tok * Hn + sch * 8;
    const unsigned short* bb = (row < 64) ? (bg + (size_t)(n0 + row) * Hn)
                                          : (bu + (size_t)(n0 + row - 64) * Hn);
    gB[i] = bb + sch * 8;
  }

  int aOff[4], bOff[4];
#pragma unroll
  for (int m = 0; m < 4; ++m) aOff[m] = (wm * 64 + m * 16 + (lane & 15)) * 64;
#pragma unroll
  for (int n = 0; n < 4; ++n)
    bOff[n] = ((n >> 1) * 64 + wn * 32 + (n & 1) * 16 + (lane & 15)) * 64;

  f32x4 acc[4][4];
#pragma unroll
  for (int m = 0; m < 4; ++m)
#pragma unroll
    for (int n = 0; n < 4; ++n) acc[m][n] = f32x4{0.f, 0.f, 0.f, 0.f};

  for (int kb = 0; kb < Hn / 64; ++kb) {
#pragma unroll
    for (int i = 0; i < 4; ++i)
      gload_lds16(gA[i] + kb * 64, &As[i * 2048 + wv * 512]);
#pragma unroll
    for (int i = 0; i < 4; ++i)
      gload_lds16(gB[i] + kb * 64, &Bs[i * 2048 + wv * 512]);
    __syncthreads();
#pragma unroll
    for (int kk = 0; kk < 2; ++kk) {
      int soff = (((kk * 4 + (lane >> 4)) ^ (lane & 7)) << 3);
      bf16x8 a[4], b[4];
#pragma unroll
      for (int m = 0; m < 4; ++m) a[m] = lds_frag(&As[aOff[m] + soff]);
#pragma unroll
      for (int n = 0; n < 4; ++n) b[n] = lds_frag(&Bs[bOff[n] + soff]);
#pragma unroll
      for (int m = 0; m < 4; ++m)
#pragma unroll
        for (int n = 0; n < 4; ++n)
          acc[m][n] = mfma16(a[m], b[n], acc[m][n]);
    }
    __syncthreads();
  }

#pragma unroll
  for (int m = 0; m < 4; ++m) {
#pragma unroll
    for (int j = 0; j < 4; ++j) {
      int r = wm * 64 + m * 16 + (lane >> 4) * 4 + j;
      if (m0 + r < cnt) {
#pragma unroll
        for (int n = 0; n < 2; ++n) {
          int col = n0 + wn * 32 + n * 16 + (lane & 15);
          float g = acc[m][n][j], u = acc[m][n + 2][j];
          float h = (g / (1.f + __expf(-g))) * u;
          hb[(size_t)(offE + m0 + r) * Nhalf + col] = f2bf(h);
        }
      }
    }
  }
}

// downA: C = h @ B^T. Routed region -> bf16*coef stores to yb;
// shared region -> plain f32 stores to out.
__global__ __launch_bounds__(256, 2)
void downA_k(const unsigned short* __restrict__ hrt, const unsigned short* __restrict__ hsh,
             const unsigned short* __restrict__ wdq, const unsigned short* __restrict__ sdq,
             const int* __restrict__ off, const int* __restrict__ counts,
             const float* __restrict__ cw,
             float* __restrict__ out, unsigned short* __restrict__ yb) {
  constexpr int NT = Hn / 128;              // 16
  constexpr int RT = En * NT * 64;          // 16384 routed tiles
  int w = blockIdx.x;
  int mi, n0, Kdim, cnt, offE;
  const unsigned short *bq, *hbuf;
  bool toYB;
  if (w < RT) {
    int e  = w >> 10;                       // / (16*64)
    int r  = w & 1023;
    int mg = r >> 7;                        // / (16*8)
    int r2 = r & 127;
    int ni = r2 >> 3, m8 = r2 & 7;
    mi = (mg << 3) | m8;
    cnt = counts[e]; offE = off[e]; Kdim = In; n0 = ni * 128;
    bq = wdq + (size_t)e * Hn * In; hbuf = hrt; toYB = true;
  } else {
    int w2 = w - RT;                        // shared: 64 M x 16 N = 1024
    int mg = w2 >> 7;
    int r2 = w2 & 127;
    int ni = r2 >> 3, m8 = r2 & 7;
    mi = (mg << 3) | m8;
    cnt = Tn; offE = 0; Kdim = ISHn; n0 = ni * 128;
    bq = sdq; hbuf = hsh; toYB = false;
  }
  int m0 = mi * 128;
  if (m0 >= cnt) return;

  __shared__ alignas(16) unsigned short As[128 * 64];
  __shared__ alignas(16) unsigned short Bs[128 * 64];

  int tid = threadIdx.x, lane = tid & 63, wv = tid >> 6;
  int wm = wv >> 1, wn = wv & 1;

  const unsigned short* gA[4];
  const unsigned short* gB[4];
#pragma unroll
  for (int i = 0; i < 4; ++i) {
    int idx = i * 256 + tid;
    int row = idx >> 3, ch = idx & 7;
    int sch = ch ^ (row & 7);
    int rc = m0 + row; rc = rc < cnt ? rc : cnt - 1;
    gA[i] = hbuf + (size_t)(offE + rc) * Kdim + sch * 8;
    gB[i] = bq + (size_t)(n0 + row) * Kdim + sch * 8;
  }

  int aOff[4], bOff[4];
#pragma unroll
  for (int m = 0; m < 4; ++m) aOff[m] = (wm * 64 + m * 16 + (lane & 15)) * 64;
#pragma unroll
  for (int n = 0; n < 4; ++n) bOff[n] = (wn * 64 + n * 16 + (lane & 15)) * 64;

  f32x4 acc[4][4];
#pragma unroll
  for (int m = 0; m < 4; ++m)
#pragma unroll
    for (int n = 0; n < 4; ++n) acc[m][n] = f32x4{0.f, 0.f, 0.f, 0.f};

  int nkb = Kdim / 64;
  for (int kb = 0; kb < nkb; ++kb) {
#pragma unroll
    for (int i = 0; i < 4; ++i)
      gload_lds16(gA[i] + kb * 64, &As[i * 2048 + wv * 512]);
#pragma unroll
    for (int i = 0; i < 4; ++i)
      gload_lds16(gB[i] + kb * 64, &Bs[i * 2048 + wv * 512]);
    __syncthreads();
#pragma unroll
    for (int kk = 0; kk < 2; ++kk) {
      int soff = (((kk * 4 + (lane >> 4)) ^ (lane & 7)) << 3);
      bf16x8 a[4], b[4];
#pragma unroll
      for (int m = 0; m < 4; ++m) a[m] = lds_frag(&As[aOff[m] + soff]);
#pragma unroll
      for (int n = 0; n < 4; ++n) b[n] = lds_frag(&Bs[bOff[n] + soff]);
#pragma unroll
      for (int m = 0; m < 4; ++m)
#pragma unroll
        for (int n = 0; n < 4; ++n)
          acc[m][n] = mfma16(a[m], b[n], acc[m][n]);
    }
    __syncthreads();
  }

#pragma unroll
  for (int m = 0; m < 4; ++m) {
#pragma unroll
    for (int j = 0; j < 4; ++j) {
      int r = wm * 64 + m * 16 + (lane >> 4) * 4 + j;
      if (m0 + r < cnt) {
        float coef = 1.f;
        if (toYB) coef = cw[offE + m0 + r];
#pragma unroll
        for (int n = 0; n < 4; ++n) {
          int col = n0 + wn * 64 + n * 16 + (lane & 15);
          float v = acc[m][n][j] * coef;
          if (toYB) yb[(size_t)(offE + m0 + r) * Hn + col] = f2bf(v);
          else out[(size_t)(m0 + r) * Hn + col] = v;
        }
      }
    }
  }
}

// ---------------- combine: out[t] += sum_k yb[rowOf[t,k]] ----------------
__global__ __launch_bounds__(256)
void combine_k(const unsigned short* __restrict__ yb, const int* __restrict__ rowOf,
               float* __restrict__ out) {
  int t = blockIdx.x;
  int c = threadIdx.x * 8;
  float* op = out + (size_t)t * Hn + c;
  float4 a0 = *reinterpret_cast<float4*>(op);
  float4 a1 = *reinterpret_cast<float4*>(op + 4);
#pragma unroll
  for (int k = 0; k < Kn; ++k) {
    int r = rowOf[t * Kn + k];
    u16x8 v = *reinterpret_cast<const u16x8*>(yb + (size_t)r * Hn + c);
    a0.x += bf2f(v[0]); a0.y += bf2f(v[1]); a0.z += bf2f(v[2]); a0.w += bf2f(v[3]);
    a1.x += bf2f(v[4]); a1.y += bf2f(v[5]); a1.z += bf2f(v[6]); a1.w += bf2f(v[7]);
  }
  *reinterpret_cast<float4*>(op) = a0;
  *reinterpret_cast<float4*>(op + 4) = a1;
}

// ======================================================================
extern "C" void kernel_launch(void* const* d_in, const int* in_sizes, int n_in,
                              void* d_out, int out_size, void* d_ws, size_t ws_size,
                              hipStream_t stream) {
  const float* x   = (const float*)d_in[0];
  const float* rg  = (const float*)d_in[1];
  const float* ru  = (const float*)d_in[2];
  const float* esc = (const float*)d_in[3];
  const float* ebi = (const float*)d_in[4];
  const float* Wg  = (const float*)d_in[5];
  const float* Wu  = (const float*)d_in[6];
  const float* Wd  = (const float*)d_in[7];
  const float* Sg  = (const float*)d_in[8];
  const float* Su  = (const float*)d_in[9];
  const float* Sd  = (const float*)d_in[10];
  float* out = (float*)d_out;

  char* ws = (char*)d_ws;

  const size_t sz_xb  = (size_t)Tn * Hn * 2;           //  33.6 MB
  const size_t sz_wgu = (size_t)En * In * Hn * 2;      //  92.3 MB each (wg,wu,wd)
  const size_t sz_sgu = (size_t)ISHn * Hn * 2;         //  11.5 MB each (sg,su,sd)
  const size_t sz_hrt = (size_t)Rn * In * 2;           //  92.3 MB
  const size_t sz_hsh = (size_t)Tn * ISHn * 2;         //  46.1 MB
  const size_t sz_misc = 1 << 20;

  size_t o = 0;
  auto take = [&](size_t b) { size_t r = o; o += (b + 255) & ~(size_t)255; return r; };
  size_t o_xb  = take(sz_xb);
  size_t o_wg  = take(sz_wgu);
  size_t o_wu  = take(sz_wgu);
  size_t o_wd  = take(sz_wgu);
  size_t o_sg  = take(sz_sgu);
  size_t o_su  = take(sz_sgu);
  size_t o_sd  = take(sz_sgu);
  size_t o_hrt = take(sz_hrt);
  size_t o_hsh = take(sz_hsh);
  size_t o_mi  = take(sz_misc);

  unsigned short* xb  = (unsigned short*)(ws + o_xb);
  unsigned short* wgq = (unsigned short*)(ws + o_wg);
  unsigned short* wuq = (unsigned short*)(ws + o_wu);
  unsigned short* wdq = (unsigned short*)(ws + o_wd);
  unsigned short* sgq = (unsigned short*)(ws + o_sg);
  unsigned short* suq = (unsigned short*)(ws + o_su);
  unsigned short* sdq = (unsigned short*)(ws + o_sd);
  unsigned short* hrt = (unsigned short*)(ws + o_hrt);
  unsigned short* hsh = (unsigned short*)(ws + o_hsh);
  char* misc = ws + o_mi;
  int*   counts = (int*)(misc);
  int*   cursor = (int*)(misc + 64);
  int*   off    = (int*)(misc + 128);
  int*   topk   = (int*)(misc + 256);
  float* wval   = (float*)(misc + 256 + 131072);
  int*   list   = (int*)(misc + 256 + 2 * 131072);
  float* cw     = (float*)(misc + 256 + 3 * 131072);
  int*   rowOf  = (int*)(misc + 256 + 4 * 131072);
  // yb aliases wg+wu bf16 region (dead after up kernel): 134.2 MB <= 184.6 MB
  unsigned short* yb = wgq;

  zero_k<<<1, 32, 0, stream>>>(counts);
  router_k<<<2048, 256, 0, stream>>>(x, rg, ru, esc, ebi, counts, topk, wval, xb);
  cvt_all<<<2048, 256, 0, stream>>>(Wg, wgq, Wu, wuq, Wd, wdq,
                                    Sg, sgq, Su, suq, Sd, sdq);
  prefix_k<<<1, 64, 0, stream>>>(counts, off);
  build_k<<<Tn / 256, 256, 0, stream>>>(topk, wval, off, cursor, list, cw, rowOf);

  // merged up: routed 22528 tiles + shared 2816 tiles (cache-blocked order)
  upA_k<<<En * (In / 64) * 64 + 64 * (ISHn / 64), 256, 0, stream>>>(
      xb, wgq, wuq, sgq, suq, list, off, counts, hrt, hsh);
  // merged down: routed 16384 tiles + shared 1024 tiles
  downA_k<<<En * (Hn / 128) * 64 + 64 * (Hn / 128), 256, 0, stream>>>(
      hrt, hsh, wdq, sdq, off, counts, cw, out, yb);
  combine_k<<<Tn, 256, 0, stream>>>(yb, rowOf, out);
}

// Round 12
// 1658.735 us; speedup vs baseline: 1.4382x; 1.0286x over previous
//
#include <hip/hip_runtime.h>
#include <hip/hip_bf16.h>
#include <cmath>

#define DEVI __device__ __forceinline__

constexpr int Hn   = 2048;   // hidden
constexpr int In   = 1408;   // per-expert intermediate
constexpr int En   = 16;     // routed experts
constexpr int Kn   = 4;      // top-k
constexpr int ISHn = 2816;   // shared intermediate
constexpr int Tn   = 8192;   // tokens (B*S)
constexpr int Rn   = Tn * Kn; // total routed rows = 32768

typedef __attribute__((ext_vector_type(4))) float f32x4;
typedef __attribute__((ext_vector_type(8))) __bf16 bf16x8;
typedef __attribute__((ext_vector_type(8))) unsigned short u16x8;

DEVI unsigned short f2bf(float f) {
  unsigned int u = __builtin_bit_cast(unsigned int, f);
  unsigned int r = (u + 0x7fffu + ((u >> 16) & 1u)) >> 16;
  return (unsigned short)r;
}
DEVI float bf2f(unsigned short h) {
  return __builtin_bit_cast(float, (unsigned int)h << 16);
}

DEVI f32x4 mfma16(bf16x8 a, bf16x8 b, f32x4 c) {
  return __builtin_amdgcn_mfma_f32_16x16x32_bf16(a, b, c, 0, 0, 0);
}

DEVI bf16x8 lds_frag(const unsigned short* p) {
  return __builtin_bit_cast(bf16x8, *reinterpret_cast<const u16x8*>(p));
}

DEVI void gload_lds16(const void* src, void* dst) {
  __builtin_amdgcn_global_load_lds(
      (const __attribute__((address_space(1))) void*)src,
      (__attribute__((address_space(3))) void*)dst, 16, 0, 0);
}

// inline exclusive scan of counts for expert e (no runtime-indexed array)
DEVI int off_of(const int* __restrict__ counts, int e) {
  int offE = 0;
#pragma unroll
  for (int i = 0; i < En; ++i) offE += (i < e) ? counts[i] : 0;
  return offE;
}

// ---------------- fp32 -> bf16 segment (vec8 grid-stride) ----------------
DEVI void cvt_seg(const float* __restrict__ in, unsigned short* __restrict__ o,
                  long n8, long t0, long stride) {
  for (long v = t0; v < n8; v += stride) {
    const float4* s = reinterpret_cast<const float4*>(in + v * 8);
    float4 a = s[0], b = s[1];
    u16x8 r;
    r[0] = f2bf(a.x); r[1] = f2bf(a.y); r[2] = f2bf(a.z); r[3] = f2bf(a.w);
    r[4] = f2bf(b.x); r[5] = f2bf(b.y); r[6] = f2bf(b.z); r[7] = f2bf(b.w);
    reinterpret_cast<u16x8*>(o)[v] = r;
  }
}

// ---------------- zero counts + cursor ----------------
__global__ void zero_k(int* p) { p[threadIdx.x] = 0; }

// ---------------- pre_k: router (blocks 0..2047) ∥ weight-cvt (2048..4095) ----
// Independent work co-resident on the device: latency-bound fp64 router hides
// under the BW-bound weight conversion stream.
__global__ __launch_bounds__(256)
void pre_k(const float* __restrict__ x, const float* __restrict__ rg,
           const float* __restrict__ ru, const float* __restrict__ esc,
           const float* __restrict__ ebi, int* __restrict__ counts,
           int* __restrict__ topk, float* __restrict__ wval,
           unsigned short* __restrict__ xb,
           const float* __restrict__ Wg, unsigned short* __restrict__ wgq,
           const float* __restrict__ Wu, unsigned short* __restrict__ wuq,
           const float* __restrict__ Wd, unsigned short* __restrict__ wdq,
           const float* __restrict__ Sg, unsigned short* __restrict__ sgq,
           const float* __restrict__ Su, unsigned short* __restrict__ suq,
           const float* __restrict__ Sd, unsigned short* __restrict__ sdq) {
  if (blockIdx.x >= 2048) {
    long stride = 2048L * 256;
    long t0 = (blockIdx.x - 2048L) * 256 + threadIdx.x;
    const long n8_w = (long)En * In * Hn / 8;
    const long n8_s = (long)ISHn * Hn / 8;
    cvt_seg(Wg, wgq, n8_w, t0, stride);
    cvt_seg(Wu, wuq, n8_w, t0, stride);
    cvt_seg(Wd, wdq, n8_w, t0, stride);
    cvt_seg(Sg, sgq, n8_s, t0, stride);
    cvt_seg(Su, suq, n8_s, t0, stride);
    cvt_seg(Sd, sdq, n8_s, t0, stride);
    return;
  }

  // ---- router: one wave per token, fp64 scoring; also emits bf16 xb ----
  int w = (blockIdx.x * blockDim.x + threadIdx.x) >> 6;
  int lane = threadIdx.x & 63;
  if (w >= Tn) return;
  const float* xr = x + (size_t)w * Hn;
  float xv[Hn / 64];
#pragma unroll
  for (int j = 0; j < Hn / 64; ++j) xv[j] = xr[lane + j * 64];

  unsigned short* xbr = xb + (size_t)w * Hn;
#pragma unroll
  for (int j = 0; j < Hn / 64; ++j) xbr[lane + j * 64] = f2bf(xv[j]);

  double pr[En];
  double mx = -1e300;
#pragma unroll
  for (int e = 0; e < En; ++e) {
    const float* gr = rg + (size_t)e * Hn;
    const float* ur = ru + (size_t)e * Hn;
    double pg = 0.0, pu = 0.0;
#pragma unroll
    for (int j = 0; j < Hn / 64; ++j) {
      pg += (double)xv[j] * (double)gr[lane + j * 64];
      pu += (double)xv[j] * (double)ur[lane + j * 64];
    }
#pragma unroll
    for (int s = 32; s > 0; s >>= 1) {
      pg += __shfl_xor(pg, s);
      pu += __shfl_xor(pu, s);
    }
    double sg = pg / (1.0 + exp(-pg));     // silu
    double sc = fabs(pu * sg);
    pr[e] = sc;
    mx = fmax(mx, sc);
  }
  double den = 0.0;
#pragma unroll
  for (int e = 0; e < En; ++e) { pr[e] = exp(pr[e] - mx); den += pr[e]; }

  if (lane == 0) {
    double invden = 1.0 / den;
    unsigned chosen = 0;
    for (int k = 0; k < Kn; ++k) {
      double bv = -1e300; int best = 0;
#pragma unroll
      for (int e = 0; e < En; ++e) {
        double be = pr[e] * invden + (double)ebi[e];
        if (!((chosen >> e) & 1u) && be > bv) { bv = be; best = e; }
      }
      chosen |= 1u << best;
      topk[w * Kn + k] = best;
      double pbest = bv - (double)ebi[best];
      wval[w * Kn + k] = (float)(1.0 + pbest * (double)esc[best]);
      atomicAdd(&counts[best], 1);
    }
  }
}

// ---------------- build per-expert token lists + token->row map ----------------
__global__ void build_k(const int* __restrict__ topk, const float* __restrict__ wval,
                        const int* __restrict__ counts, int* __restrict__ cursor,
                        int* __restrict__ list, float* __restrict__ cw,
                        int* __restrict__ rowOf) {
  int t = blockIdx.x * blockDim.x + threadIdx.x;
  if (t >= Tn) return;
  for (int k = 0; k < Kn; ++k) {
    int e = topk[t * Kn + k];
    int offE = off_of(counts, e);
    int pos = atomicAdd(&cursor[e], 1);
    int r = offE + pos;
    list[r] = t;
    cw[r] = wval[t * Kn + k];
    rowOf[t * Kn + k] = r;
  }
}

// ======================================================================
// GEMMs: proven 2-barrier inner loop (128-row tiles, single-buffer 32KB
// LDS, XOR-swizzled, global_load_lds staging). Merged routed+shared 1D
// grids with CACHE-BLOCKED work order: (e, m-group-of-8, n, m-within).
// Default (round-robin) dispatch — XCD chunk remap measured -67% here.
// ======================================================================

// upA: h = silu(A@Bg^T) * (A@Bu^T). Block computes 128 rows x 64 cols of h.
// Bs rows 0-63 = Bg rows n0.., rows 64-127 = Bu rows (same cols).
// Fragment n=0,1 -> g, n=2,3 -> u of the SAME output columns (same thread).
__global__ __launch_bounds__(256, 2)
void upA_k(const unsigned short* __restrict__ xb,
           const unsigned short* __restrict__ WgA, const unsigned short* __restrict__ WuA,
           const unsigned short* __restrict__ SgA, const unsigned short* __restrict__ SuA,
           const int* __restrict__ list, const int* __restrict__ counts,
           unsigned short* __restrict__ hrt, unsigned short* __restrict__ hsh) {
  constexpr int NTr = In / 64;              // 22
  constexpr int RT  = En * NTr * 64;        // 22528 routed tiles
  int w = blockIdx.x;
  int mi, n0, Nhalf, cnt, offE;
  const unsigned short *bg, *bu;
  unsigned short* hb;
  bool gat;
  if (w < RT) {
    int e  = w / (NTr * 64);                // /1408
    int r  = w - e * (NTr * 64);
    int mg = r / (NTr * 8);                 // /176
    int r2 = r - mg * (NTr * 8);
    int ni = r2 >> 3, m8 = r2 & 7;
    mi = (mg << 3) | m8;
    cnt = counts[e]; offE = off_of(counts, e); Nhalf = In; n0 = ni * 64;
    size_t es = (size_t)In * Hn;
    bg = WgA + (size_t)e * es; bu = WuA + (size_t)e * es;
    hb = hrt; gat = true;
  } else {
    int w2 = w - RT;                        // shared: 64 M x 44 N = 2816
    int mg = w2 / (44 * 8);                 // /352
    int r2 = w2 - mg * (44 * 8);
    int ni = r2 >> 3, m8 = r2 & 7;
    mi = (mg << 3) | m8;
    cnt = Tn; offE = 0; Nhalf = ISHn; n0 = ni * 64;
    bg = SgA; bu = SuA; hb = hsh; gat = false;
  }
  int m0 = mi * 128;
  if (m0 >= cnt) return;

  __shared__ alignas(16) unsigned short As[128 * 64];
  __shared__ alignas(16) unsigned short Bs[128 * 64];

  int tid = threadIdx.x, lane = tid & 63, wv = tid >> 6;
  int wm = wv >> 1, wn = wv & 1;

  const unsigned short* gA[4];
  const unsigned short* gB[4];
#pragma unroll
  for (int i = 0; i < 4; ++i) {
    int idx = i * 256 + tid;
    int row = idx >> 3, ch = idx & 7;
    int sch = ch ^ (row & 7);
    int rc = m0 + row; rc = rc < cnt ? rc : cnt - 1;
    int tok = gat ? list[offE + rc] : rc;
    gA[i] = xb + (size_t)tok * Hn + sch * 8;
    const unsigned short* bb = (row < 64) ? (bg + (size_t)(n0 + row) * Hn)
                                          : (bu + (size_t)(n0 + row - 64) * Hn);
    gB[i] = bb + sch * 8;
  }

  int aOff[4], bOff[4];
#pragma unroll
  for (int m = 0; m < 4; ++m) aOff[m] = (wm * 64 + m * 16 + (lane & 15)) * 64;
#pragma unroll
  for (int n = 0; n < 4; ++n)
    bOff[n] = ((n >> 1) * 64 + wn * 32 + (n & 1) * 16 + (lane & 15)) * 64;

  f32x4 acc[4][4];
#pragma unroll
  for (int m = 0; m < 4; ++m)
#pragma unroll
    for (int n = 0; n < 4; ++n) acc[m][n] = f32x4{0.f, 0.f, 0.f, 0.f};

  for (int kb = 0; kb < Hn / 64; ++kb) {
#pragma unroll
    for (int i = 0; i < 4; ++i)
      gload_lds16(gA[i] + kb * 64, &As[i * 2048 + wv * 512]);
#pragma unroll
    for (int i = 0; i < 4; ++i)
      gload_lds16(gB[i] + kb * 64, &Bs[i * 2048 + wv * 512]);
    __syncthreads();
#pragma unroll
    for (int kk = 0; kk < 2; ++kk) {
      int soff = (((kk * 4 + (lane >> 4)) ^ (lane & 7)) << 3);
      bf16x8 a[4], b[4];
#pragma unroll
      for (int m = 0; m < 4; ++m) a[m] = lds_frag(&As[aOff[m] + soff]);
#pragma unroll
      for (int n = 0; n < 4; ++n) b[n] = lds_frag(&Bs[bOff[n] + soff]);
#pragma unroll
      for (int m = 0; m < 4; ++m)
#pragma unroll
        for (int n = 0; n < 4; ++n)
          acc[m][n] = mfma16(a[m], b[n], acc[m][n]);
    }
    __syncthreads();
  }

#pragma unroll
  for (int m = 0; m < 4; ++m) {
#pragma unroll
    for (int j = 0; j < 4; ++j) {
      int r = wm * 64 + m * 16 + (lane >> 4) * 4 + j;
      if (m0 + r < cnt) {
#pragma unroll
        for (int n = 0; n < 2; ++n) {
          int col = n0 + wn * 32 + n * 16 + (lane & 15);
          float g = acc[m][n][j], u = acc[m][n + 2][j];
          float h = (g / (1.f + __expf(-g))) * u;
          hb[(size_t)(offE + m0 + r) * Nhalf + col] = f2bf(h);
        }
      }
    }
  }
}

// downA: C = h @ B^T. Routed region -> bf16*coef stores to yb;
// shared region -> plain f32 stores to out.
__global__ __launch_bounds__(256, 2)
void downA_k(const unsigned short* __restrict__ hrt, const unsigned short* __restrict__ hsh,
             const unsigned short* __restrict__ wdq, const unsigned short* __restrict__ sdq,
             const int* __restrict__ counts, const float* __restrict__ cw,
             float* __restrict__ out, unsigned short* __restrict__ yb) {
  constexpr int NT = Hn / 128;              // 16
  constexpr int RT = En * NT * 64;          // 16384 routed tiles
  int w = blockIdx.x;
  int mi, n0, Kdim, cnt, offE;
  const unsigned short *bq, *hbuf;
  bool toYB;
  if (w < RT) {
    int e  = w >> 10;                       // / (16*64)
    int r  = w & 1023;
    int mg = r >> 7;                        // / (16*8)
    int r2 = r & 127;
    int ni = r2 >> 3, m8 = r2 & 7;
    mi = (mg << 3) | m8;
    cnt = counts[e]; offE = off_of(counts, e); Kdim = In; n0 = ni * 128;
    bq = wdq + (size_t)e * Hn * In; hbuf = hrt; toYB = true;
  } else {
    int w2 = w - RT;                        // shared: 64 M x 16 N = 1024
    int mg = w2 >> 7;
    int r2 = w2 & 127;
    int ni = r2 >> 3, m8 = r2 & 7;
    mi = (mg << 3) | m8;
    cnt = Tn; offE = 0; Kdim = ISHn; n0 = ni * 128;
    bq = sdq; hbuf = hsh; toYB = false;
  }
  int m0 = mi * 128;
  if (m0 >= cnt) return;

  __shared__ alignas(16) unsigned short As[128 * 64];
  __shared__ alignas(16) unsigned short Bs[128 * 64];

  int tid = threadIdx.x, lane = tid & 63, wv = tid >> 6;
  int wm = wv >> 1, wn = wv & 1;

  const unsigned short* gA[4];
  const unsigned short* gB[4];
#pragma unroll
  for (int i = 0; i < 4; ++i) {
    int idx = i * 256 + tid;
    int row = idx >> 3, ch = idx & 7;
    int sch = ch ^ (row & 7);
    int rc = m0 + row; rc = rc < cnt ? rc : cnt - 1;
    gA[i] = hbuf + (size_t)(offE + rc) * Kdim + sch * 8;
    gB[i] = bq + (size_t)(n0 + row) * Kdim + sch * 8;
  }

  int aOff[4], bOff[4];
#pragma unroll
  for (int m = 0; m < 4; ++m) aOff[m] = (wm * 64 + m * 16 + (lane & 15)) * 64;
#pragma unroll
  for (int n = 0; n < 4; ++n) bOff[n] = (wn * 64 + n * 16 + (lane & 15)) * 64;

  f32x4 acc[4][4];
#pragma unroll
  for (int m = 0; m < 4; ++m)
#pragma unroll
    for (int n = 0; n < 4; ++n) acc[m][n] = f32x4{0.f, 0.f, 0.f, 0.f};

  int nkb = Kdim / 64;
  for (int kb = 0; kb < nkb; ++kb) {
#pragma unroll
    for (int i = 0; i < 4; ++i)
      gload_lds16(gA[i] + kb * 64, &As[i * 2048 + wv * 512]);
#pragma unroll
    for (int i = 0; i < 4; ++i)
      gload_lds16(gB[i] + kb * 64, &Bs[i * 2048 + wv * 512]);
    __syncthreads();
#pragma unroll
    for (int kk = 0; kk < 2; ++kk) {
      int soff = (((kk * 4 + (lane >> 4)) ^ (lane & 7)) << 3);
      bf16x8 a[4], b[4];
#pragma unroll
      for (int m = 0; m < 4; ++m) a[m] = lds_frag(&As[aOff[m] + soff]);
#pragma unroll
      for (int n = 0; n < 4; ++n) b[n] = lds_frag(&Bs[bOff[n] + soff]);
#pragma unroll
      for (int m = 0; m < 4; ++m)
#pragma unroll
        for (int n = 0; n < 4; ++n)
          acc[m][n] = mfma16(a[m], b[n], acc[m][n]);
    }
    __syncthreads();
  }

#pragma unroll
  for (int m = 0; m < 4; ++m) {
#pragma unroll
    for (int j = 0; j < 4; ++j) {
      int r = wm * 64 + m * 16 + (lane >> 4) * 4 + j;
      if (m0 + r < cnt) {
        float coef = 1.f;
        if (toYB) coef = cw[offE + m0 + r];
#pragma unroll
        for (int n = 0; n < 4; ++n) {
          int col = n0 + wn * 64 + n * 16 + (lane & 15);
          float v = acc[m][n][j] * coef;
          if (toYB) yb[(size_t)(offE + m0 + r) * Hn + col] = f2bf(v);
          else out[(size_t)(m0 + r) * Hn + col] = v;
        }
      }
    }
  }
}

// ---------------- combine: out[t] += sum_k yb[rowOf[t,k]] ----------------
__global__ __launch_bounds__(256)
void combine_k(const unsigned short* __restrict__ yb, const int* __restrict__ rowOf,
               float* __restrict__ out) {
  int t = blockIdx.x;
  int c = threadIdx.x * 8;
  float* op = out + (size_t)t * Hn + c;
  float4 a0 = *reinterpret_cast<float4*>(op);
  float4 a1 = *reinterpret_cast<float4*>(op + 4);
#pragma unroll
  for (int k = 0; k < Kn; ++k) {
    int r = rowOf[t * Kn + k];
    u16x8 v = *reinterpret_cast<const u16x8*>(yb + (size_t)r * Hn + c);
    a0.x += bf2f(v[0]); a0.y += bf2f(v[1]); a0.z += bf2f(v[2]); a0.w += bf2f(v[3]);
    a1.x += bf2f(v[4]); a1.y += bf2f(v[5]); a1.z += bf2f(v[6]); a1.w += bf2f(v[7]);
  }
  *reinterpret_cast<float4*>(op) = a0;
  *reinterpret_cast<float4*>(op + 4) = a1;
}

// ======================================================================
extern "C" void kernel_launch(void* const* d_in, const int* in_sizes, int n_in,
                              void* d_out, int out_size, void* d_ws, size_t ws_size,
                              hipStream_t stream) {
  const float* x   = (const float*)d_in[0];
  const float* rg  = (const float*)d_in[1];
  const float* ru  = (const float*)d_in[2];
  const float* esc = (const float*)d_in[3];
  const float* ebi = (const float*)d_in[4];
  const float* Wg  = (const float*)d_in[5];
  const float* Wu  = (const float*)d_in[6];
  const float* Wd  = (const float*)d_in[7];
  const float* Sg  = (const float*)d_in[8];
  const float* Su  = (const float*)d_in[9];
  const float* Sd  = (const float*)d_in[10];
  float* out = (float*)d_out;

  char* ws = (char*)d_ws;

  const size_t sz_xb  = (size_t)Tn * Hn * 2;           //  33.6 MB
  const size_t sz_wgu = (size_t)En * In * Hn * 2;      //  92.3 MB each (wg,wu,wd)
  const size_t sz_sgu = (size_t)ISHn * Hn * 2;         //  11.5 MB each (sg,su,sd)
  const size_t sz_hrt = (size_t)Rn * In * 2;           //  92.3 MB
  const size_t sz_hsh = (size_t)Tn * ISHn * 2;         //  46.1 MB
  const size_t sz_misc = 1 << 20;

  size_t o = 0;
  auto take = [&](size_t b) { size_t r = o; o += (b + 255) & ~(size_t)255; return r; };
  size_t o_xb  = take(sz_xb);
  size_t o_wg  = take(sz_wgu);
  size_t o_wu  = take(sz_wgu);
  size_t o_wd  = take(sz_wgu);
  size_t o_sg  = take(sz_sgu);
  size_t o_su  = take(sz_sgu);
  size_t o_sd  = take(sz_sgu);
  size_t o_hrt = take(sz_hrt);
  size_t o_hsh = take(sz_hsh);
  size_t o_mi  = take(sz_misc);

  unsigned short* xb  = (unsigned short*)(ws + o_xb);
  unsigned short* wgq = (unsigned short*)(ws + o_wg);
  unsigned short* wuq = (unsigned short*)(ws + o_wu);
  unsigned short* wdq = (unsigned short*)(ws + o_wd);
  unsigned short* sgq = (unsigned short*)(ws + o_sg);
  unsigned short* suq = (unsigned short*)(ws + o_su);
  unsigned short* sdq = (unsigned short*)(ws + o_sd);
  unsigned short* hrt = (unsigned short*)(ws + o_hrt);
  unsigned short* hsh = (unsigned short*)(ws + o_hsh);
  char* misc = ws + o_mi;
  int*   counts = (int*)(misc);
  int*   cursor = (int*)(misc + 64);
  int*   topk   = (int*)(misc + 256);
  float* wval   = (float*)(misc + 256 + 131072);
  int*   list   = (int*)(misc + 256 + 2 * 131072);
  float* cw     = (float*)(misc + 256 + 3 * 131072);
  int*   rowOf  = (int*)(misc + 256 + 4 * 131072);
  // yb aliases wg+wu bf16 region (dead after up kernel): 134.2 MB <= 184.6 MB
  unsigned short* yb = wgq;

  zero_k<<<1, 32, 0, stream>>>(counts);
  // router (2048 blocks) ∥ weight conversion (2048 blocks), co-resident
  pre_k<<<4096, 256, 0, stream>>>(x, rg, ru, esc, ebi, counts, topk, wval, xb,
                                  Wg, wgq, Wu, wuq, Wd, wdq,
                                  Sg, sgq, Su, suq, Sd, sdq);
  build_k<<<Tn / 256, 256, 0, stream>>>(topk, wval, counts, cursor, list, cw, rowOf);

  // merged up: routed 22528 tiles + shared 2816 tiles (cache-blocked order)
  upA_k<<<En * (In / 64) * 64 + 64 * (ISHn / 64), 256, 0, stream>>>(
      xb, wgq, wuq, sgq, suq, list, counts, hrt, hsh);
  // merged down: routed 16384 tiles + shared 1024 tiles
  downA_k<<<En * (Hn / 128) * 64 + 64 * (Hn / 128), 256, 0, stream>>>(
      hrt, hsh, wdq, sdq, counts, cw, out, yb);
  combine_k<<<Tn, 256, 0, stream>>>(yb, rowOf, out);
}

// Round 13
// 1632.935 us; speedup vs baseline: 1.4609x; 1.0158x over previous
//
#include <hip/hip_runtime.h>
#include <hip/hip_bf16.h>
#include <cmath>

#define DEVI __device__ __forceinline__

constexpr int Hn   = 2048;   // hidden
constexpr int In   = 1408;   // per-expert intermediate
constexpr int En   = 16;     // routed experts
constexpr int Kn   = 4;      // top-k
constexpr int ISHn = 2816;   // shared intermediate
constexpr int Tn   = 8192;   // tokens (B*S)
constexpr int Rn   = Tn * Kn; // total routed rows = 32768

typedef __attribute__((ext_vector_type(4))) float f32x4;
typedef __attribute__((ext_vector_type(8))) __bf16 bf16x8;
typedef __attribute__((ext_vector_type(8))) unsigned short u16x8;

DEVI unsigned short f2bf(float f) {
  unsigned int u = __builtin_bit_cast(unsigned int, f);
  unsigned int r = (u + 0x7fffu + ((u >> 16) & 1u)) >> 16;
  return (unsigned short)r;
}
DEVI float bf2f(unsigned short h) {
  return __builtin_bit_cast(float, (unsigned int)h << 16);
}

DEVI f32x4 mfma16(bf16x8 a, bf16x8 b, f32x4 c) {
  return __builtin_amdgcn_mfma_f32_16x16x32_bf16(a, b, c, 0, 0, 0);
}

DEVI bf16x8 lds_frag(const unsigned short* p) {
  return __builtin_bit_cast(bf16x8, *reinterpret_cast<const u16x8*>(p));
}

DEVI void gload_lds16(const void* src, void* dst) {
  __builtin_amdgcn_global_load_lds(
      (const __attribute__((address_space(1))) void*)src,
      (__attribute__((address_space(3))) void*)dst, 16, 0, 0);
}

// inline exclusive scan of counts for expert e (no runtime-indexed array)
DEVI int off_of(const int* __restrict__ counts, int e) {
  int offE = 0;
#pragma unroll
  for (int i = 0; i < En; ++i) offE += (i < e) ? counts[i] : 0;
  return offE;
}

// ---------------- fp32 -> bf16 segment (vec8 grid-stride) ----------------
DEVI void cvt_seg(const float* __restrict__ in, unsigned short* __restrict__ o,
                  long n8, long t0, long stride) {
  for (long v = t0; v < n8; v += stride) {
    const float4* s = reinterpret_cast<const float4*>(in + v * 8);
    float4 a = s[0], b = s[1];
    u16x8 r;
    r[0] = f2bf(a.x); r[1] = f2bf(a.y); r[2] = f2bf(a.z); r[3] = f2bf(a.w);
    r[4] = f2bf(b.x); r[5] = f2bf(b.y); r[6] = f2bf(b.z); r[7] = f2bf(b.w);
    reinterpret_cast<u16x8*>(o)[v] = r;
  }
}

// ---------------- zero counts + cursor ----------------
__global__ void zero_k(int* p) { p[threadIdx.x] = 0; }

// ---------------- pre_k: router (blocks 0..2047) ∥ up-weight cvt (2048..4095) --
// Wd/Sd conversion deferred to upA's grid head (not needed until downA).
__global__ __launch_bounds__(256)
void pre_k(const float* __restrict__ x, const float* __restrict__ rg,
           const float* __restrict__ ru, const float* __restrict__ esc,
           const float* __restrict__ ebi, int* __restrict__ counts,
           int* __restrict__ topk, float* __restrict__ wval,
           unsigned short* __restrict__ xb,
           const float* __restrict__ Wg, unsigned short* __restrict__ wgq,
           const float* __restrict__ Wu, unsigned short* __restrict__ wuq,
           const float* __restrict__ Sg, unsigned short* __restrict__ sgq,
           const float* __restrict__ Su, unsigned short* __restrict__ suq) {
  if (blockIdx.x >= 2048) {
    long stride = 2048L * 256;
    long t0 = (blockIdx.x - 2048L) * 256 + threadIdx.x;
    const long n8_w = (long)En * In * Hn / 8;
    const long n8_s = (long)ISHn * Hn / 8;
    cvt_seg(Wg, wgq, n8_w, t0, stride);
    cvt_seg(Wu, wuq, n8_w, t0, stride);
    cvt_seg(Sg, sgq, n8_s, t0, stride);
    cvt_seg(Su, suq, n8_s, t0, stride);
    return;
  }

  // ---- router: one wave per token, fp64 scoring; also emits bf16 xb ----
  int w = (blockIdx.x * blockDim.x + threadIdx.x) >> 6;
  int lane = threadIdx.x & 63;
  if (w >= Tn) return;
  const float* xr = x + (size_t)w * Hn;
  float xv[Hn / 64];
#pragma unroll
  for (int j = 0; j < Hn / 64; ++j) xv[j] = xr[lane + j * 64];

  unsigned short* xbr = xb + (size_t)w * Hn;
#pragma unroll
  for (int j = 0; j < Hn / 64; ++j) xbr[lane + j * 64] = f2bf(xv[j]);

  double pr[En];
  double mx = -1e300;
#pragma unroll
  for (int e = 0; e < En; ++e) {
    const float* gr = rg + (size_t)e * Hn;
    const float* ur = ru + (size_t)e * Hn;
    double pg = 0.0, pu = 0.0;
#pragma unroll
    for (int j = 0; j < Hn / 64; ++j) {
      pg += (double)xv[j] * (double)gr[lane + j * 64];
      pu += (double)xv[j] * (double)ur[lane + j * 64];
    }
#pragma unroll
    for (int s = 32; s > 0; s >>= 1) {
      pg += __shfl_xor(pg, s);
      pu += __shfl_xor(pu, s);
    }
    double sg = pg / (1.0 + exp(-pg));     // silu
    double sc = fabs(pu * sg);
    pr[e] = sc;
    mx = fmax(mx, sc);
  }
  double den = 0.0;
#pragma unroll
  for (int e = 0; e < En; ++e) { pr[e] = exp(pr[e] - mx); den += pr[e]; }

  if (lane == 0) {
    double invden = 1.0 / den;
    unsigned chosen = 0;
    for (int k = 0; k < Kn; ++k) {
      double bv = -1e300; int best = 0;
#pragma unroll
      for (int e = 0; e < En; ++e) {
        double be = pr[e] * invden + (double)ebi[e];
        if (!((chosen >> e) & 1u) && be > bv) { bv = be; best = e; }
      }
      chosen |= 1u << best;
      topk[w * Kn + k] = best;
      double pbest = bv - (double)ebi[best];
      wval[w * Kn + k] = (float)(1.0 + pbest * (double)esc[best]);
      atomicAdd(&counts[best], 1);
    }
  }
}

// ---------------- build per-expert token lists + token->row map ----------------
__global__ void build_k(const int* __restrict__ topk, const float* __restrict__ wval,
                        const int* __restrict__ counts, int* __restrict__ cursor,
                        int* __restrict__ list, float* __restrict__ cw,
                        int* __restrict__ rowOf) {
  int t = blockIdx.x * blockDim.x + threadIdx.x;
  if (t >= Tn) return;
  for (int k = 0; k < Kn; ++k) {
    int e = topk[t * Kn + k];
    int offE = off_of(counts, e);
    int pos = atomicAdd(&cursor[e], 1);
    int r = offE + pos;
    list[r] = t;
    cw[r] = wval[t * Kn + k];
    rowOf[t * Kn + k] = r;
  }
}

// ======================================================================
// GEMMs: proven 2-barrier inner loop (128-row tiles, single-buffer 32KB
// LDS, XOR-swizzled, global_load_lds staging). Merged routed+shared 1D
// grids with CACHE-BLOCKED work order: (e, m-group-of-8, n, m-within).
// Default (round-robin) dispatch — XCD chunk remap measured -67% here.
// upA additionally carries 1024 leading blocks that stream-convert
// Wd/Sd to bf16 (consumed only by downA), hiding that traffic under
// upA's latency-bound profile.
// ======================================================================

// upA: h = silu(A@Bg^T) * (A@Bu^T). Block computes 128 rows x 64 cols of h.
// Bs rows 0-63 = Bg rows n0.., rows 64-127 = Bu rows (same cols).
// Fragment n=0,1 -> g, n=2,3 -> u of the SAME output columns (same thread).
__global__ __launch_bounds__(256, 2)
void upA_k(const unsigned short* __restrict__ xb,
           const unsigned short* __restrict__ WgA, const unsigned short* __restrict__ WuA,
           const unsigned short* __restrict__ SgA, const unsigned short* __restrict__ SuA,
           const int* __restrict__ list, const int* __restrict__ counts,
           unsigned short* __restrict__ hrt, unsigned short* __restrict__ hsh,
           const float* __restrict__ Wd, unsigned short* __restrict__ wdq,
           const float* __restrict__ Sd, unsigned short* __restrict__ sdq) {
  constexpr int CVT = 1024;                 // leading cvt blocks (Wd+Sd)
  constexpr int NTr = In / 64;              // 22
  constexpr int RT  = En * NTr * 64;        // 22528 routed tiles
  if (blockIdx.x < CVT) {
    long stride = (long)CVT * 256;
    long t0 = blockIdx.x * 256L + threadIdx.x;
    const long n8_wd = (long)En * In * Hn / 8;
    const long n8_sd = (long)ISHn * Hn / 8;
    cvt_seg(Wd, wdq, n8_wd, t0, stride);
    cvt_seg(Sd, sdq, n8_sd, t0, stride);
    return;
  }
  int w = blockIdx.x - CVT;
  int mi, n0, Nhalf, cnt, offE;
  const unsigned short *bg, *bu;
  unsigned short* hb;
  bool gat;
  if (w < RT) {
    int e  = w / (NTr * 64);                // /1408
    int r  = w - e * (NTr * 64);
    int mg = r / (NTr * 8);                 // /176
    int r2 = r - mg * (NTr * 8);
    int ni = r2 >> 3, m8 = r2 & 7;
    mi = (mg << 3) | m8;
    cnt = counts[e]; offE = off_of(counts, e); Nhalf = In; n0 = ni * 64;
    size_t es = (size_t)In * Hn;
    bg = WgA + (size_t)e * es; bu = WuA + (size_t)e * es;
    hb = hrt; gat = true;
  } else {
    int w2 = w - RT;                        // shared: 64 M x 44 N = 2816
    int mg = w2 / (44 * 8);                 // /352
    int r2 = w2 - mg * (44 * 8);
    int ni = r2 >> 3, m8 = r2 & 7;
    mi = (mg << 3) | m8;
    cnt = Tn; offE = 0; Nhalf = ISHn; n0 = ni * 64;
    bg = SgA; bu = SuA; hb = hsh; gat = false;
  }
  int m0 = mi * 128;
  if (m0 >= cnt) return;

  __shared__ alignas(16) unsigned short As[128 * 64];
  __shared__ alignas(16) unsigned short Bs[128 * 64];

  int tid = threadIdx.x, lane = tid & 63, wv = tid >> 6;
  int wm = wv >> 1, wn = wv & 1;

  const unsigned short* gA[4];
  const unsigned short* gB[4];
#pragma unroll
  for (int i = 0; i < 4; ++i) {
    int idx = i * 256 + tid;
    int row = idx >> 3, ch = idx & 7;
    int sch = ch ^ (row & 7);
    int rc = m0 + row; rc = rc < cnt ? rc : cnt - 1;
    int tok = gat ? list[offE + rc] : rc;
    gA[i] = xb + (size_t)tok * Hn + sch * 8;
    const unsigned short* bb = (row < 64) ? (bg + (size_t)(n0 + row) * Hn)
                                          : (bu + (size_t)(n0 + row - 64) * Hn);
    gB[i] = bb + sch * 8;
  }

  int aOff[4], bOff[4];
#pragma unroll
  for (int m = 0; m < 4; ++m) aOff[m] = (wm * 64 + m * 16 + (lane & 15)) * 64;
#pragma unroll
  for (int n = 0; n < 4; ++n)
    bOff[n] = ((n >> 1) * 64 + wn * 32 + (n & 1) * 16 + (lane & 15)) * 64;

  f32x4 acc[4][4];
#pragma unroll
  for (int m = 0; m < 4; ++m)
#pragma unroll
    for (int n = 0; n < 4; ++n) acc[m][n] = f32x4{0.f, 0.f, 0.f, 0.f};

  for (int kb = 0; kb < Hn / 64; ++kb) {
#pragma unroll
    for (int i = 0; i < 4; ++i)
      gload_lds16(gA[i] + kb * 64, &As[i * 2048 + wv * 512]);
#pragma unroll
    for (int i = 0; i < 4; ++i)
      gload_lds16(gB[i] + kb * 64, &Bs[i * 2048 + wv * 512]);
    __syncthreads();
#pragma unroll
    for (int kk = 0; kk < 2; ++kk) {
      int soff = (((kk * 4 + (lane >> 4)) ^ (lane & 7)) << 3);
      bf16x8 a[4], b[4];
#pragma unroll
      for (int m = 0; m < 4; ++m) a[m] = lds_frag(&As[aOff[m] + soff]);
#pragma unroll
      for (int n = 0; n < 4; ++n) b[n] = lds_frag(&Bs[bOff[n] + soff]);
#pragma unroll
      for (int m = 0; m < 4; ++m)
#pragma unroll
        for (int n = 0; n < 4; ++n)
          acc[m][n] = mfma16(a[m], b[n], acc[m][n]);
    }
    __syncthreads();
  }

#pragma unroll
  for (int m = 0; m < 4; ++m) {
#pragma unroll
    for (int j = 0; j < 4; ++j) {
      int r = wm * 64 + m * 16 + (lane >> 4) * 4 + j;
      if (m0 + r < cnt) {
#pragma unroll
        for (int n = 0; n < 2; ++n) {
          int col = n0 + wn * 32 + n * 16 + (lane & 15);
          float g = acc[m][n][j], u = acc[m][n + 2][j];
          float h = (g / (1.f + __expf(-g))) * u;
          hb[(size_t)(offE + m0 + r) * Nhalf + col] = f2bf(h);
        }
      }
    }
  }
}

// downA: C = h @ B^T. Routed region -> bf16*coef stores to yb;
// shared region -> plain f32 stores to out.
__global__ __launch_bounds__(256, 2)
void downA_k(const unsigned short* __restrict__ hrt, const unsigned short* __restrict__ hsh,
             const unsigned short* __restrict__ wdq, const unsigned short* __restrict__ sdq,
             const int* __restrict__ counts, const float* __restrict__ cw,
             float* __restrict__ out, unsigned short* __restrict__ yb) {
  constexpr int NT = Hn / 128;              // 16
  constexpr int RT = En * NT * 64;          // 16384 routed tiles
  int w = blockIdx.x;
  int mi, n0, Kdim, cnt, offE;
  const unsigned short *bq, *hbuf;
  bool toYB;
  if (w < RT) {
    int e  = w >> 10;                       // / (16*64)
    int r  = w & 1023;
    int mg = r >> 7;                        // / (16*8)
    int r2 = r & 127;
    int ni = r2 >> 3, m8 = r2 & 7;
    mi = (mg << 3) | m8;
    cnt = counts[e]; offE = off_of(counts, e); Kdim = In; n0 = ni * 128;
    bq = wdq + (size_t)e * Hn * In; hbuf = hrt; toYB = true;
  } else {
    int w2 = w - RT;                        // shared: 64 M x 16 N = 1024
    int mg = w2 >> 7;
    int r2 = w2 & 127;
    int ni = r2 >> 3, m8 = r2 & 7;
    mi = (mg << 3) | m8;
    cnt = Tn; offE = 0; Kdim = ISHn; n0 = ni * 128;
    bq = sdq; hbuf = hsh; toYB = false;
  }
  int m0 = mi * 128;
  if (m0 >= cnt) return;

  __shared__ alignas(16) unsigned short As[128 * 64];
  __shared__ alignas(16) unsigned short Bs[128 * 64];

  int tid = threadIdx.x, lane = tid & 63, wv = tid >> 6;
  int wm = wv >> 1, wn = wv & 1;

  const unsigned short* gA[4];
  const unsigned short* gB[4];
#pragma unroll
  for (int i = 0; i < 4; ++i) {
    int idx = i * 256 + tid;
    int row = idx >> 3, ch = idx & 7;
    int sch = ch ^ (row & 7);
    int rc = m0 + row; rc = rc < cnt ? rc : cnt - 1;
    gA[i] = hbuf + (size_t)(offE + rc) * Kdim + sch * 8;
    gB[i] = bq + (size_t)(n0 + row) * Kdim + sch * 8;
  }

  int aOff[4], bOff[4];
#pragma unroll
  for (int m = 0; m < 4; ++m) aOff[m] = (wm * 64 + m * 16 + (lane & 15)) * 64;
#pragma unroll
  for (int n = 0; n < 4; ++n) bOff[n] = (wn * 64 + n * 16 + (lane & 15)) * 64;

  f32x4 acc[4][4];
#pragma unroll
  for (int m = 0; m < 4; ++m)
#pragma unroll
    for (int n = 0; n < 4; ++n) acc[m][n] = f32x4{0.f, 0.f, 0.f, 0.f};

  int nkb = Kdim / 64;
  for (int kb = 0; kb < nkb; ++kb) {
#pragma unroll
    for (int i = 0; i < 4; ++i)
      gload_lds16(gA[i] + kb * 64, &As[i * 2048 + wv * 512]);
#pragma unroll
    for (int i = 0; i < 4; ++i)
      gload_lds16(gB[i] + kb * 64, &Bs[i * 2048 + wv * 512]);
    __syncthreads();
#pragma unroll
    for (int kk = 0; kk < 2; ++kk) {
      int soff = (((kk * 4 + (lane >> 4)) ^ (lane & 7)) << 3);
      bf16x8 a[4], b[4];
#pragma unroll
      for (int m = 0; m < 4; ++m) a[m] = lds_frag(&As[aOff[m] + soff]);
#pragma unroll
      for (int n = 0; n < 4; ++n) b[n] = lds_frag(&Bs[bOff[n] + soff]);
#pragma unroll
      for (int m = 0; m < 4; ++m)
#pragma unroll
        for (int n = 0; n < 4; ++n)
          acc[m][n] = mfma16(a[m], b[n], acc[m][n]);
    }
    __syncthreads();
  }

#pragma unroll
  for (int m = 0; m < 4; ++m) {
#pragma unroll
    for (int j = 0; j < 4; ++j) {
      int r = wm * 64 + m * 16 + (lane >> 4) * 4 + j;
      if (m0 + r < cnt) {
        float coef = 1.f;
        if (toYB) coef = cw[offE + m0 + r];
#pragma unroll
        for (int n = 0; n < 4; ++n) {
          int col = n0 + wn * 64 + n * 16 + (lane & 15);
          float v = acc[m][n][j] * coef;
          if (toYB) yb[(size_t)(offE + m0 + r) * Hn + col] = f2bf(v);
          else out[(size_t)(m0 + r) * Hn + col] = v;
        }
      }
    }
  }
}

// ---------------- combine: out[t] += sum_k yb[rowOf[t,k]] ----------------
__global__ __launch_bounds__(256)
void combine_k(const unsigned short* __restrict__ yb, const int* __restrict__ rowOf,
               float* __restrict__ out) {
  int t = blockIdx.x;
  int c = threadIdx.x * 8;
  float* op = out + (size_t)t * Hn + c;
  float4 a0 = *reinterpret_cast<float4*>(op);
  float4 a1 = *reinterpret_cast<float4*>(op + 4);
#pragma unroll
  for (int k = 0; k < Kn; ++k) {
    int r = rowOf[t * Kn + k];
    u16x8 v = *reinterpret_cast<const u16x8*>(yb + (size_t)r * Hn + c);
    a0.x += bf2f(v[0]); a0.y += bf2f(v[1]); a0.z += bf2f(v[2]); a0.w += bf2f(v[3]);
    a1.x += bf2f(v[4]); a1.y += bf2f(v[5]); a1.z += bf2f(v[6]); a1.w += bf2f(v[7]);
  }
  *reinterpret_cast<float4*>(op) = a0;
  *reinterpret_cast<float4*>(op + 4) = a1;
}

// ======================================================================
extern "C" void kernel_launch(void* const* d_in, const int* in_sizes, int n_in,
                              void* d_out, int out_size, void* d_ws, size_t ws_size,
                              hipStream_t stream) {
  const float* x   = (const float*)d_in[0];
  const float* rg  = (const float*)d_in[1];
  const float* ru  = (const float*)d_in[2];
  const float* esc = (const float*)d_in[3];
  const float* ebi = (const float*)d_in[4];
  const float* Wg  = (const float*)d_in[5];
  const float* Wu  = (const float*)d_in[6];
  const float* Wd  = (const float*)d_in[7];
  const float* Sg  = (const float*)d_in[8];
  const float* Su  = (const float*)d_in[9];
  const float* Sd  = (const float*)d_in[10];
  float* out = (float*)d_out;

  char* ws = (char*)d_ws;

  const size_t sz_xb  = (size_t)Tn * Hn * 2;           //  33.6 MB
  const size_t sz_wgu = (size_t)En * In * Hn * 2;      //  92.3 MB each (wg,wu,wd)
  const size_t sz_sgu = (size_t)ISHn * Hn * 2;         //  11.5 MB each (sg,su,sd)
  const size_t sz_hrt = (size_t)Rn * In * 2;           //  92.3 MB
  const size_t sz_hsh = (size_t)Tn * ISHn * 2;         //  46.1 MB
  const size_t sz_misc = 1 << 20;

  size_t o = 0;
  auto take = [&](size_t b) { size_t r = o; o += (b + 255) & ~(size_t)255; return r; };
  size_t o_xb  = take(sz_xb);
  size_t o_wg  = take(sz_wgu);
  size_t o_wu  = take(sz_wgu);
  size_t o_wd  = take(sz_wgu);
  size_t o_sg  = take(sz_sgu);
  size_t o_su  = take(sz_sgu);
  size_t o_sd  = take(sz_sgu);
  size_t o_hrt = take(sz_hrt);
  size_t o_hsh = take(sz_hsh);
  size_t o_mi  = take(sz_misc);

  unsigned short* xb  = (unsigned short*)(ws + o_xb);
  unsigned short* wgq = (unsigned short*)(ws + o_wg);
  unsigned short* wuq = (unsigned short*)(ws + o_wu);
  unsigned short* wdq = (unsigned short*)(ws + o_wd);
  unsigned short* sgq = (unsigned short*)(ws + o_sg);
  unsigned short* suq = (unsigned short*)(ws + o_su);
  unsigned short* sdq = (unsigned short*)(ws + o_sd);
  unsigned short* hrt = (unsigned short*)(ws + o_hrt);
  unsigned short* hsh = (unsigned short*)(ws + o_hsh);
  char* misc = ws + o_mi;
  int*   counts = (int*)(misc);
  int*   cursor = (int*)(misc + 64);
  int*   topk   = (int*)(misc + 256);
  float* wval   = (float*)(misc + 256 + 131072);
  int*   list   = (int*)(misc + 256 + 2 * 131072);
  float* cw     = (float*)(misc + 256 + 3 * 131072);
  int*   rowOf  = (int*)(misc + 256 + 4 * 131072);
  // yb aliases wg+wu bf16 region (dead after up kernel): 134.2 MB <= 184.6 MB
  unsigned short* yb = wgq;

  zero_k<<<1, 32, 0, stream>>>(counts);
  // router (2048 blocks) ∥ up-weight conversion (2048 blocks), co-resident
  pre_k<<<4096, 256, 0, stream>>>(x, rg, ru, esc, ebi, counts, topk, wval, xb,
                                  Wg, wgq, Wu, wuq, Sg, sgq, Su, suq);
  build_k<<<Tn / 256, 256, 0, stream>>>(topk, wval, counts, cursor, list, cw, rowOf);

  // merged up: 1024 cvt blocks (Wd/Sd) + routed 22528 tiles + shared 2816 tiles
  upA_k<<<1024 + En * (In / 64) * 64 + 64 * (ISHn / 64), 256, 0, stream>>>(
      xb, wgq, wuq, sgq, suq, list, counts, hrt, hsh, Wd, wdq, Sd, sdq);
  // merged down: routed 16384 tiles + shared 1024 tiles
  downA_k<<<En * (Hn / 128) * 64 + 64 * (Hn / 128), 256, 0, stream>>>(
      hrt, hsh, wdq, sdq, counts, cw, out, yb);
  combine_k<<<Tn, 256, 0, stream>>>(yb, rowOf, out);
}